// Round 1
// baseline (393.389 us; speedup 1.0000x reference)
//
#include <hip/hip_runtime.h>
#include <hip/hip_bf16.h>

#define B_ 4
#define T_ 2048
#define C_ 1024
#define NH 16
#define HD 64
#define M_TOK (B_*T_)   // 8192

typedef unsigned short u16;
typedef __bf16 bf16x8 __attribute__((ext_vector_type(8)));
typedef short short8 __attribute__((ext_vector_type(8)));
typedef float f32x4 __attribute__((ext_vector_type(4)));
typedef unsigned short u16x4 __attribute__((ext_vector_type(4)));

static __device__ __forceinline__ u16 f2bf(float f) {
    union { float f; unsigned u; } a; a.f = f;
    unsigned u = a.u;
    u = u + 0x7fff + ((u >> 16) & 1);   // RNE
    return (u16)(u >> 16);
}

static __device__ __forceinline__ f32x4 mfma16(short8 a, short8 b, f32x4 c) {
    return __builtin_amdgcn_mfma_f32_16x16x32_bf16(
        __builtin_bit_cast(bf16x8, a), __builtin_bit_cast(bf16x8, b), c, 0, 0, 0);
}

// ---------------- elementwise fp32 -> bf16 ----------------
__global__ void convert_x(const float* __restrict__ src, u16* __restrict__ dst, int n4) {
    int i = blockIdx.x * blockDim.x + threadIdx.x;
    if (i < n4) {
        const float4 v = *(const float4*)(src + (size_t)i * 4);
        u16x4 o;
        o[0] = f2bf(v.x); o[1] = f2bf(v.y); o[2] = f2bf(v.z); o[3] = f2bf(v.w);
        *(u16x4*)(dst + (size_t)i * 4) = o;
    }
}

// ---------------- transpose fp32 [rows][cols] -> bf16 [cols][rows] ----------------
__global__ void transpose_bf16(const float* __restrict__ src, u16* __restrict__ dst,
                               int rows, int cols) {
    __shared__ float tile[32][33];
    const int c0 = blockIdx.x * 32, r0 = blockIdx.y * 32;
    const int tx = threadIdx.x, ty = threadIdx.y;
    #pragma unroll
    for (int j = ty; j < 32; j += 8)
        tile[j][tx] = src[(size_t)(r0 + j) * cols + c0 + tx];
    __syncthreads();
    #pragma unroll
    for (int j = ty; j < 32; j += 8)
        dst[(size_t)(c0 + j) * rows + r0 + tx] = f2bf(tile[tx][j]);
}

// ---------------- bf16 GEMM: C[M][N] = A[M][K] * Bt[N][K]^T + bias ----------------
// 128x128 tile, BK=32, 256 threads = 4 waves, each wave 64x64 (4x4 frags of 16x16x32)
template<int OUT_BF16>
__global__ __launch_bounds__(256) void gemm_bt(
    const u16* __restrict__ A,    // [M][K] bf16
    const u16* __restrict__ Bt,   // [N][K] bf16
    const float* __restrict__ bias, // [N]
    u16* __restrict__ Cb, float* __restrict__ Cf,
    int M, int N, int K)
{
    __shared__ u16 Al[128][40];   // +8 pad: row stride 80B -> conflict-free b128 reads
    __shared__ u16 Bl[128][40];
    const int tid  = threadIdx.x;
    const int lane = tid & 63;
    const int w    = tid >> 6;
    const int wr   = w >> 1, wc = w & 1;
    const int bm   = blockIdx.y * 128, bn = blockIdx.x * 128;

    f32x4 acc[4][4] = {};

    const int lrow = tid >> 2;          // 0..63
    const int lcol = (tid & 3) * 8;     // 0,8,16,24
    const u16* Arow0 = A  + (size_t)(bm + lrow) * K + lcol;
    const u16* Arow1 = Arow0 + (size_t)64 * K;
    const u16* Brow0 = Bt + (size_t)(bn + lrow) * K + lcol;
    const u16* Brow1 = Brow0 + (size_t)64 * K;

    const int fr = lane & 15;           // frag row/col within 16
    const int fk = (lane >> 4) * 8;     // frag k offset within 32

    for (int k0 = 0; k0 < K; k0 += 32) {
        *(short8*)&Al[lrow][lcol]      = *(const short8*)(Arow0 + k0);
        *(short8*)&Al[lrow + 64][lcol] = *(const short8*)(Arow1 + k0);
        *(short8*)&Bl[lrow][lcol]      = *(const short8*)(Brow0 + k0);
        *(short8*)&Bl[lrow + 64][lcol] = *(const short8*)(Brow1 + k0);
        __syncthreads();

        short8 af[4], bfr[4];
        #pragma unroll
        for (int m = 0; m < 4; m++) af[m]  = *(const short8*)&Al[wr * 64 + m * 16 + fr][fk];
        #pragma unroll
        for (int n = 0; n < 4; n++) bfr[n] = *(const short8*)&Bl[wc * 64 + n * 16 + fr][fk];
        #pragma unroll
        for (int m = 0; m < 4; m++)
            #pragma unroll
            for (int n = 0; n < 4; n++)
                acc[m][n] = mfma16(af[m], bfr[n], acc[m][n]);
        __syncthreads();
    }

    // epilogue: D row = (lane>>4)*4 + i, col = lane&15
    const int r0 = (lane >> 4) * 4;
    #pragma unroll
    for (int m = 0; m < 4; m++) {
        #pragma unroll
        for (int i = 0; i < 4; i++) {
            const int grow = bm + wr * 64 + m * 16 + r0 + i;
            #pragma unroll
            for (int n = 0; n < 4; n++) {
                const int gcol = bn + wc * 64 + n * 16 + fr;
                const float v = acc[m][n][i] + bias[gcol];
                if (OUT_BF16) Cb[(size_t)grow * N + gcol] = f2bf(v);
                else          Cf[(size_t)grow * N + gcol] = v;
            }
        }
    }
}

// ---------------- causal flash attention ----------------
// grid: (T/64, B*NH). block: 256 threads = 4 waves; wave v owns q rows [qt*64+v*16, +16)
__global__ __launch_bounds__(256) void attn_fwd(
    const u16* __restrict__ qkv,   // [M_TOK][3C] bf16
    u16* __restrict__ out)         // [M_TOK][C] bf16
{
    __shared__ u16 Kl[64][72];     // [kv][d], pad 8
    __shared__ u16 Vt[64][72];     // [d][kv], pad 8
    __shared__ u16 Pl[4][16][72];  // per-wave P, [qrow][kv], pad 8

    const int tid  = threadIdx.x;
    const int lane = tid & 63;
    const int wv   = tid >> 6;
    const int bh = blockIdx.y;
    const int b = bh >> 4, h = bh & 15;
    const int qt = blockIdx.x;
    const int tok0 = b * T_;
    const int qrow_base = qt * 64 + wv * 16;   // within sequence
    const int fr = lane & 15;
    const int fg = lane >> 4;
    const int fk = fg * 8;

    // Q fragments (A-operand): row=fr, k = fk+j (+32 for second chunk)
    short8 aq[2];
    {
        const u16* qp = qkv + (size_t)(tok0 + qrow_base + fr) * (3 * C_) + h * HD;
        aq[0] = *(const short8*)(qp + fk);
        aq[1] = *(const short8*)(qp + 32 + fk);
    }

    f32x4 oacc[4] = {};
    float mrow[4], lsum[4];
    #pragma unroll
    for (int i = 0; i < 4; i++) { mrow[i] = -INFINITY; lsum[i] = 0.f; }

    const int ntiles = qt + 1;
    for (int kt = 0; kt < ntiles; ++kt) {
        // stage K [64][64] and V transposed [d][kv]
        {
            const int kvr = tid >> 2;
            const int kc  = (tid & 3) * 8;
            const u16* kp = qkv + (size_t)(tok0 + kt * 64 + kvr) * (3 * C_) + C_ + h * HD;
            *(short8*)&Kl[kvr][kc]      = *(const short8*)(kp + kc);
            *(short8*)&Kl[kvr][kc + 32] = *(const short8*)(kp + kc + 32);
            const u16* vp = qkv + (size_t)(tok0 + kt * 64 + kvr) * (3 * C_) + 2 * C_ + h * HD;
            const short8 v0 = *(const short8*)(vp + kc);
            const short8 v1 = *(const short8*)(vp + kc + 32);
            #pragma unroll
            for (int j = 0; j < 8; j++) {
                Vt[kc + j][kvr]      = (u16)v0[j];
                Vt[kc + 32 + j][kvr] = (u16)v1[j];
            }
        }
        __syncthreads();

        // S = Q K^T  (S row = q, col = kv)
        f32x4 s[4] = {};
        #pragma unroll
        for (int fc = 0; fc < 4; fc++) {
            short8 bk0 = *(const short8*)&Kl[fc * 16 + fr][fk];
            short8 bk1 = *(const short8*)&Kl[fc * 16 + fr][32 + fk];
            s[fc] = mfma16(aq[0], bk0, s[fc]);
            s[fc] = mfma16(aq[1], bk1, s[fc]);
        }

        // scale + causal mask + per-lane max
        float pmax[4];
        #pragma unroll
        for (int i = 0; i < 4; i++) pmax[i] = -INFINITY;
        const int qg = qrow_base + fg * 4;       // + i
        const int kvg = kt * 64 + fr;            // + fc*16
        #pragma unroll
        for (int fc = 0; fc < 4; fc++) {
            #pragma unroll
            for (int i = 0; i < 4; i++) {
                float sv = s[fc][i] * 0.125f;
                if (kvg + fc * 16 > qg + i) sv = -INFINITY;
                s[fc][i] = sv;
                pmax[i] = fmaxf(pmax[i], sv);
            }
        }
        // reduce max over the 16 lanes of this row group
        #pragma unroll
        for (int d = 1; d < 16; d <<= 1) {
            #pragma unroll
            for (int i = 0; i < 4; i++)
                pmax[i] = fmaxf(pmax[i], __shfl_xor(pmax[i], d, 64));
        }
        // online softmax update
        float psum[4] = {0.f, 0.f, 0.f, 0.f};
        #pragma unroll
        for (int i = 0; i < 4; i++) {
            const float mnew = fmaxf(mrow[i], pmax[i]);
            const float alpha = __expf(mrow[i] - mnew);  // exp(-inf)=0
            mrow[i] = mnew;
            lsum[i] *= alpha;
            #pragma unroll
            for (int df = 0; df < 4; df++) oacc[df][i] *= alpha;
        }
        #pragma unroll
        for (int fc = 0; fc < 4; fc++) {
            #pragma unroll
            for (int i = 0; i < 4; i++) {
                const float p = __expf(s[fc][i] - mrow[i]);
                psum[i] += p;
                Pl[wv][fg * 4 + i][fc * 16 + fr] = f2bf(p);
            }
        }
        #pragma unroll
        for (int d = 1; d < 16; d <<= 1) {
            #pragma unroll
            for (int i = 0; i < 4; i++)
                psum[i] += __shfl_xor(psum[i], d, 64);
        }
        #pragma unroll
        for (int i = 0; i < 4; i++) lsum[i] += psum[i];

        // make our own wave's Pl writes visible to our ds_reads
        asm volatile("s_waitcnt lgkmcnt(0)" ::: "memory");

        // O += P @ V   (A = P[q][kv] from Pl, B = Vt[d][kv] k-major)
        #pragma unroll
        for (int c = 0; c < 2; c++) {
            const short8 ap = *(const short8*)&Pl[wv][fr][c * 32 + fk];
            #pragma unroll
            for (int df = 0; df < 4; df++) {
                const short8 bv = *(const short8*)&Vt[df * 16 + fr][c * 32 + fk];
                oacc[df] = mfma16(ap, bv, oacc[df]);
            }
        }
        __syncthreads();
    }

    // write normalized output
    #pragma unroll
    for (int i = 0; i < 4; i++) {
        const float inv = 1.f / lsum[i];
        const int tokn = tok0 + qrow_base + fg * 4 + i;
        #pragma unroll
        for (int df = 0; df < 4; df++) {
            out[(size_t)tokn * C_ + h * HD + df * 16 + fr] = f2bf(oacc[df][i] * inv);
        }
    }
}

extern "C" void kernel_launch(void* const* d_in, const int* in_sizes, int n_in,
                              void* d_out, int out_size, void* d_ws, size_t ws_size,
                              hipStream_t stream) {
    const float* hs    = (const float*)d_in[0];
    const float* w_qkv = (const float*)d_in[1];
    const float* b_qkv = (const float*)d_in[2];
    const float* w_o   = (const float*)d_in[3];
    const float* b_o   = (const float*)d_in[4];
    float* out = (float*)d_out;

    u16* Xb    = (u16*)d_ws;                            // [8192][1024]
    u16* WqkvT = Xb    + (size_t)M_TOK * C_;            // [3072][1024]
    u16* WoT   = WqkvT + (size_t)3 * C_ * C_;           // [1024][1024]
    u16* QKV   = WoT   + (size_t)C_ * C_;               // [8192][3072]
    u16* AO    = QKV   + (size_t)M_TOK * 3 * C_;        // [8192][1024]

    // fp32 -> bf16 conversions / weight transposes
    {
        const int n4 = M_TOK * C_ / 4;
        convert_x<<<(n4 + 255) / 256, 256, 0, stream>>>(hs, Xb, n4);
        dim3 tb(32, 8);
        transpose_bf16<<<dim3(3 * C_ / 32, C_ / 32), tb, 0, stream>>>(w_qkv, WqkvT, C_, 3 * C_);
        transpose_bf16<<<dim3(C_ / 32, C_ / 32), tb, 0, stream>>>(w_o, WoT, C_, C_);
    }

    // QKV projection: [8192][3072]
    gemm_bt<1><<<dim3(3 * C_ / 128, M_TOK / 128), 256, 0, stream>>>(
        Xb, WqkvT, b_qkv, QKV, nullptr, M_TOK, 3 * C_, C_);

    // causal attention -> AO [8192][1024]
    attn_fwd<<<dim3(T_ / 64, B_ * NH), 256, 0, stream>>>(QKV, AO);

    // output projection: fp32 out
    gemm_bt<0><<<dim3(C_ / 128, M_TOK / 128), 256, 0, stream>>>(
        AO, WoT, b_o, nullptr, out, M_TOK, C_, C_);
}

// Round 2
// 286.913 us; speedup vs baseline: 1.3711x; 1.3711x over previous
//
#include <hip/hip_runtime.h>
#include <hip/hip_bf16.h>

#define B_ 4
#define T_ 2048
#define C_ 1024
#define NH 16
#define HD 64
#define M_TOK (B_*T_)   // 8192

typedef unsigned short u16;
typedef __bf16 bf16x8 __attribute__((ext_vector_type(8)));
typedef short short8 __attribute__((ext_vector_type(8)));
typedef float f32x4 __attribute__((ext_vector_type(4)));
typedef unsigned short u16x4 __attribute__((ext_vector_type(4)));

static __device__ __forceinline__ u16 f2bf(float f) {
    union { float f; unsigned u; } a; a.f = f;
    unsigned u = a.u;
    u = u + 0x7fff + ((u >> 16) & 1);   // RNE
    return (u16)(u >> 16);
}

static __device__ __forceinline__ f32x4 mfma16(short8 a, short8 b, f32x4 c) {
    return __builtin_amdgcn_mfma_f32_16x16x32_bf16(
        __builtin_bit_cast(bf16x8, a), __builtin_bit_cast(bf16x8, b), c, 0, 0, 0);
}

// ---------------- elementwise fp32 -> bf16 ----------------
__global__ void convert_x(const float* __restrict__ src, u16* __restrict__ dst, int n4) {
    int i = blockIdx.x * blockDim.x + threadIdx.x;
    if (i < n4) {
        const float4 v = *(const float4*)(src + (size_t)i * 4);
        u16x4 o;
        o[0] = f2bf(v.x); o[1] = f2bf(v.y); o[2] = f2bf(v.z); o[3] = f2bf(v.w);
        *(u16x4*)(dst + (size_t)i * 4) = o;
    }
}

// ---------------- transpose fp32 [rows][cols] -> bf16 [cols][rows] ----------------
__global__ void transpose_bf16(const float* __restrict__ src, u16* __restrict__ dst,
                               int rows, int cols) {
    __shared__ float tile[32][33];
    const int c0 = blockIdx.x * 32, r0 = blockIdx.y * 32;
    const int tx = threadIdx.x, ty = threadIdx.y;
    #pragma unroll
    for (int j = ty; j < 32; j += 8)
        tile[j][tx] = src[(size_t)(r0 + j) * cols + c0 + tx];
    __syncthreads();
    #pragma unroll
    for (int j = ty; j < 32; j += 8)
        dst[(size_t)(c0 + j) * rows + r0 + tx] = f2bf(tile[tx][j]);
}

// ---------------- bf16 GEMM: C[M][N] = A[M][K] * Bt[N][K]^T + bias ----------------
template<int OUT_BF16>
__global__ __launch_bounds__(256) void gemm_bt(
    const u16* __restrict__ A,    // [M][K] bf16
    const u16* __restrict__ Bt,   // [N][K] bf16
    const float* __restrict__ bias, // [N]
    u16* __restrict__ Cb, float* __restrict__ Cf,
    int M, int N, int K)
{
    __shared__ u16 Al[128][40];
    __shared__ u16 Bl[128][40];
    const int tid  = threadIdx.x;
    const int lane = tid & 63;
    const int w    = tid >> 6;
    const int wr   = w >> 1, wc = w & 1;
    const int bm   = blockIdx.y * 128, bn = blockIdx.x * 128;

    f32x4 acc[4][4] = {};

    const int lrow = tid >> 2;
    const int lcol = (tid & 3) * 8;
    const u16* Arow0 = A  + (size_t)(bm + lrow) * K + lcol;
    const u16* Arow1 = Arow0 + (size_t)64 * K;
    const u16* Brow0 = Bt + (size_t)(bn + lrow) * K + lcol;
    const u16* Brow1 = Brow0 + (size_t)64 * K;

    const int fr = lane & 15;
    const int fk = (lane >> 4) * 8;

    for (int k0 = 0; k0 < K; k0 += 32) {
        *(short8*)&Al[lrow][lcol]      = *(const short8*)(Arow0 + k0);
        *(short8*)&Al[lrow + 64][lcol] = *(const short8*)(Arow1 + k0);
        *(short8*)&Bl[lrow][lcol]      = *(const short8*)(Brow0 + k0);
        *(short8*)&Bl[lrow + 64][lcol] = *(const short8*)(Brow1 + k0);
        __syncthreads();

        short8 af[4], bfr[4];
        #pragma unroll
        for (int m = 0; m < 4; m++) af[m]  = *(const short8*)&Al[wr * 64 + m * 16 + fr][fk];
        #pragma unroll
        for (int n = 0; n < 4; n++) bfr[n] = *(const short8*)&Bl[wc * 64 + n * 16 + fr][fk];
        #pragma unroll
        for (int m = 0; m < 4; m++)
            #pragma unroll
            for (int n = 0; n < 4; n++)
                acc[m][n] = mfma16(af[m], bfr[n], acc[m][n]);
        __syncthreads();
    }

    const int r0 = (lane >> 4) * 4;
    #pragma unroll
    for (int m = 0; m < 4; m++) {
        #pragma unroll
        for (int i = 0; i < 4; i++) {
            const int grow = bm + wr * 64 + m * 16 + r0 + i;
            #pragma unroll
            for (int n = 0; n < 4; n++) {
                const int gcol = bn + wc * 64 + n * 16 + fr;
                const float v = acc[m][n][i] + bias[gcol];
                if (OUT_BF16) Cb[(size_t)grow * N + gcol] = f2bf(v);
                else          Cf[(size_t)grow * N + gcol] = v;
            }
        }
    }
}

// ---------------- causal flash attention v2 ----------------
// 1-D grid of 1024 blocks; block = 4 waves; wave owns 32 q rows (block = 128).
// KV tile = 64. V stored transposed in LDS with kv-block XOR swizzle.
__global__ __launch_bounds__(256, 4) void attn_fwd(
    const u16* __restrict__ qkv,   // [M_TOK][3C] bf16
    u16* __restrict__ out)         // [M_TOK][C] bf16
{
    __shared__ u16 Kl[64][72];     // [kv][d]
    __shared__ u16 Vt[64][72];     // [d][kv-swizzled], cols 0..63 used
    __shared__ u16 Pl[4][32][72];  // per-wave P [qlocal][kv]

    const int tid  = threadIdx.x;
    const int lane = tid & 63;
    const int wv   = tid >> 6;
    const int bid  = blockIdx.x;
    const int head = bid >> 4;             // 0..63
    const int b = head >> 4, h = head & 15;
    // balance: each CU's 4 resident blocks get spread qt values; heavy-first.
    const int qt = 15 - (((bid & 15) + ((bid >> 8) << 2)) & 15);
    const int tok0 = b * T_;
    const int q0 = qt * 128 + wv * 32;     // wave's first q row (within seq)
    const int fr = lane & 15;
    const int fg = lane >> 4;
    const int fk = fg * 8;

    // Q fragments: [rg][k-chunk]
    short8 aq[2][2];
    #pragma unroll
    for (int rg = 0; rg < 2; rg++) {
        const u16* qp = qkv + (size_t)(tok0 + q0 + rg * 16 + fr) * (3 * C_) + h * HD;
        aq[rg][0] = *(const short8*)(qp + fk);
        aq[rg][1] = *(const short8*)(qp + 32 + fk);
    }

    f32x4 oacc[2][4] = {};
    float mrow[2][4], lsum[2][4];
    #pragma unroll
    for (int rg = 0; rg < 2; rg++)
        #pragma unroll
        for (int i = 0; i < 4; i++) { mrow[rg][i] = -INFINITY; lsum[rg][i] = 0.f; }

    // staging indices
    const int kvr = tid >> 2;              // 0..63
    const int kc  = (tid & 3) * 8;         // 0,8,16,24
    const int vcol = (kvr & 7) + 8 * ((kvr >> 3) ^ (tid & 3));   // swizzled kv col

    const int ntiles = 2 * qt + 2;
    for (int kt = 0; kt < ntiles; ++kt) {
        const u16* kp = qkv + (size_t)(tok0 + kt * 64 + kvr) * (3 * C_) + C_ + h * HD;
        *(short8*)&Kl[kvr][kc]      = *(const short8*)(kp + kc);
        *(short8*)&Kl[kvr][kc + 32] = *(const short8*)(kp + kc + 32);
        const u16* vp = kp + C_;
        const short8 v0 = *(const short8*)(vp + kc);
        const short8 v1 = *(const short8*)(vp + kc + 32);
        #pragma unroll
        for (int j = 0; j < 8; j++) {
            Vt[kc + j][vcol]      = (u16)v0[j];
            Vt[kc + 32 + j][vcol] = (u16)v1[j];
        }
        __syncthreads();

        if (kt * 64 <= q0 + 31) {          // wave-uniform skip of fully-masked tiles
            #pragma unroll
            for (int rg = 0; rg < 2; rg++) {
                f32x4 s[4] = {};
                #pragma unroll
                for (int fc = 0; fc < 4; fc++) {
                    const short8 bk0 = *(const short8*)&Kl[fc * 16 + fr][fk];
                    const short8 bk1 = *(const short8*)&Kl[fc * 16 + fr][32 + fk];
                    s[fc] = mfma16(aq[rg][0], bk0, s[fc]);
                    s[fc] = mfma16(aq[rg][1], bk1, s[fc]);
                }
                float pmax[4];
                #pragma unroll
                for (int i = 0; i < 4; i++) pmax[i] = -INFINITY;
                const int qg = q0 + rg * 16 + fg * 4;
                const int kvg = kt * 64 + fr;
                #pragma unroll
                for (int fc = 0; fc < 4; fc++) {
                    #pragma unroll
                    for (int i = 0; i < 4; i++) {
                        float sv = s[fc][i] * 0.125f;
                        if (kvg + fc * 16 > qg + i) sv = -INFINITY;
                        s[fc][i] = sv;
                        pmax[i] = fmaxf(pmax[i], sv);
                    }
                }
                #pragma unroll
                for (int d = 1; d < 16; d <<= 1)
                    #pragma unroll
                    for (int i = 0; i < 4; i++)
                        pmax[i] = fmaxf(pmax[i], __shfl_xor(pmax[i], d, 64));
                float psum[4] = {0.f, 0.f, 0.f, 0.f};
                #pragma unroll
                for (int i = 0; i < 4; i++) {
                    const float mnew = fmaxf(mrow[rg][i], pmax[i]);
                    const float alpha = __expf(mrow[rg][i] - mnew);
                    mrow[rg][i] = mnew;
                    lsum[rg][i] *= alpha;
                    #pragma unroll
                    for (int df = 0; df < 4; df++) oacc[rg][df][i] *= alpha;
                }
                #pragma unroll
                for (int fc = 0; fc < 4; fc++) {
                    #pragma unroll
                    for (int i = 0; i < 4; i++) {
                        const float p = __expf(s[fc][i] - mrow[rg][i]);
                        psum[i] += p;
                        Pl[wv][rg * 16 + fg * 4 + i][fc * 16 + fr] = f2bf(p);
                    }
                }
                #pragma unroll
                for (int d = 1; d < 16; d <<= 1)
                    #pragma unroll
                    for (int i = 0; i < 4; i++)
                        psum[i] += __shfl_xor(psum[i], d, 64);
                #pragma unroll
                for (int i = 0; i < 4; i++) lsum[rg][i] += psum[i];
            }

            // our own wave's Pl writes must land before ds_reads below
            asm volatile("s_waitcnt lgkmcnt(0)" ::: "memory");

            #pragma unroll
            for (int rg = 0; rg < 2; rg++) {
                #pragma unroll
                for (int c = 0; c < 2; c++) {
                    const short8 ap = *(const short8*)&Pl[wv][rg * 16 + fr][c * 32 + fk];
                    #pragma unroll
                    for (int df = 0; df < 4; df++) {
                        const int sd = (df * 2 + (fr >> 3)) & 3;
                        const short8 bv = *(const short8*)&Vt[df * 16 + fr][8 * (((c << 2) + fg) ^ sd)];
                        oacc[rg][df] = mfma16(ap, bv, oacc[rg][df]);
                    }
                }
            }
        }
        __syncthreads();
    }

    #pragma unroll
    for (int rg = 0; rg < 2; rg++) {
        #pragma unroll
        for (int i = 0; i < 4; i++) {
            const float inv = 1.f / lsum[rg][i];
            const int tokn = tok0 + q0 + rg * 16 + fg * 4 + i;
            #pragma unroll
            for (int df = 0; df < 4; df++)
                out[(size_t)tokn * C_ + h * HD + df * 16 + fr] = f2bf(oacc[rg][df][i] * inv);
        }
    }
}

extern "C" void kernel_launch(void* const* d_in, const int* in_sizes, int n_in,
                              void* d_out, int out_size, void* d_ws, size_t ws_size,
                              hipStream_t stream) {
    const float* hs    = (const float*)d_in[0];
    const float* w_qkv = (const float*)d_in[1];
    const float* b_qkv = (const float*)d_in[2];
    const float* w_o   = (const float*)d_in[3];
    const float* b_o   = (const float*)d_in[4];
    float* out = (float*)d_out;

    u16* Xb    = (u16*)d_ws;                            // [8192][1024]
    u16* WqkvT = Xb    + (size_t)M_TOK * C_;            // [3072][1024]
    u16* WoT   = WqkvT + (size_t)3 * C_ * C_;           // [1024][1024]
    u16* QKV   = WoT   + (size_t)C_ * C_;               // [8192][3072]
    u16* AO    = QKV   + (size_t)M_TOK * 3 * C_;        // [8192][1024]

    {
        const int n4 = M_TOK * C_ / 4;
        convert_x<<<(n4 + 255) / 256, 256, 0, stream>>>(hs, Xb, n4);
        dim3 tb(32, 8);
        transpose_bf16<<<dim3(3 * C_ / 32, C_ / 32), tb, 0, stream>>>(w_qkv, WqkvT, C_, 3 * C_);
        transpose_bf16<<<dim3(C_ / 32, C_ / 32), tb, 0, stream>>>(w_o, WoT, C_, C_);
    }

    gemm_bt<1><<<dim3(3 * C_ / 128, M_TOK / 128), 256, 0, stream>>>(
        Xb, WqkvT, b_qkv, QKV, nullptr, M_TOK, 3 * C_, C_);

    attn_fwd<<<dim3(T_ / 128 * B_ * NH), 256, 0, stream>>>(QKV, AO);

    gemm_bt<0><<<dim3(C_ / 128, M_TOK / 128), 256, 0, stream>>>(
        AO, WoT, b_o, nullptr, out, M_TOK, C_, C_);
}

// Round 3
// 249.018 us; speedup vs baseline: 1.5798x; 1.1522x over previous
//
#include <hip/hip_runtime.h>
#include <hip/hip_bf16.h>

#define B_ 4
#define T_ 2048
#define C_ 1024
#define NH 16
#define HD 64
#define M_TOK (B_*T_)   // 8192

typedef unsigned short u16;
typedef __bf16 bf16x8 __attribute__((ext_vector_type(8)));
typedef short short8 __attribute__((ext_vector_type(8)));
typedef float f32x4 __attribute__((ext_vector_type(4)));
typedef unsigned u32x4 __attribute__((ext_vector_type(4)));
typedef unsigned short u16x4 __attribute__((ext_vector_type(4)));

static __device__ __forceinline__ u16 f2bf(float f) {
    union { float f; unsigned u; } a; a.f = f;
    unsigned u = a.u;
    u = u + 0x7fff + ((u >> 16) & 1);   // RNE
    return (u16)(u >> 16);
}

static __device__ __forceinline__ unsigned cvtpk(float lo, float hi) {
    unsigned r;
    asm("v_cvt_pk_bf16_f32 %0, %1, %2" : "=v"(r) : "v"(lo), "v"(hi));
    return r;
}

static __device__ __forceinline__ f32x4 mfma16(short8 a, short8 b, f32x4 c) {
    return __builtin_amdgcn_mfma_f32_16x16x32_bf16(
        __builtin_bit_cast(bf16x8, a), __builtin_bit_cast(bf16x8, b), c, 0, 0, 0);
}

// ---------------- elementwise fp32 -> bf16 ----------------
__global__ void convert_x(const float* __restrict__ src, u16* __restrict__ dst, int n4) {
    int i = blockIdx.x * blockDim.x + threadIdx.x;
    if (i < n4) {
        const float4 v = *(const float4*)(src + (size_t)i * 4);
        u16x4 o;
        o[0] = f2bf(v.x); o[1] = f2bf(v.y); o[2] = f2bf(v.z); o[3] = f2bf(v.w);
        *(u16x4*)(dst + (size_t)i * 4) = o;
    }
}

// ---------------- transpose fp32 [rows][cols] -> bf16 [cols][rows] ----------------
__global__ void transpose_bf16(const float* __restrict__ src, u16* __restrict__ dst,
                               int rows, int cols) {
    __shared__ float tile[32][33];
    const int c0 = blockIdx.x * 32, r0 = blockIdx.y * 32;
    const int tx = threadIdx.x, ty = threadIdx.y;
    #pragma unroll
    for (int j = ty; j < 32; j += 8)
        tile[j][tx] = src[(size_t)(r0 + j) * cols + c0 + tx];
    __syncthreads();
    #pragma unroll
    for (int j = ty; j < 32; j += 8)
        dst[(size_t)(c0 + j) * rows + r0 + tx] = f2bf(tile[tx][j]);
}

// ---------------- bf16 GEMM: C[M][N] = A[M][K] * Bt[N][K]^T + bias ----------------
// scale_ncols: output columns < scale_ncols are multiplied by 0.125 (Q pre-scaling)
template<int OUT_BF16>
__global__ __launch_bounds__(256) void gemm_bt(
    const u16* __restrict__ A,    // [M][K] bf16
    const u16* __restrict__ Bt,   // [N][K] bf16
    const float* __restrict__ bias, // [N]
    u16* __restrict__ Cb, float* __restrict__ Cf,
    int M, int N, int K, int scale_ncols)
{
    __shared__ u16 Al[128][40];
    __shared__ u16 Bl[128][40];
    const int tid  = threadIdx.x;
    const int lane = tid & 63;
    const int w    = tid >> 6;
    const int wr   = w >> 1, wc = w & 1;
    const int bm   = blockIdx.y * 128, bn = blockIdx.x * 128;

    f32x4 acc[4][4] = {};

    const int lrow = tid >> 2;
    const int lcol = (tid & 3) * 8;
    const u16* Arow0 = A  + (size_t)(bm + lrow) * K + lcol;
    const u16* Arow1 = Arow0 + (size_t)64 * K;
    const u16* Brow0 = Bt + (size_t)(bn + lrow) * K + lcol;
    const u16* Brow1 = Brow0 + (size_t)64 * K;

    const int fr = lane & 15;
    const int fk = (lane >> 4) * 8;

    for (int k0 = 0; k0 < K; k0 += 32) {
        *(short8*)&Al[lrow][lcol]      = *(const short8*)(Arow0 + k0);
        *(short8*)&Al[lrow + 64][lcol] = *(const short8*)(Arow1 + k0);
        *(short8*)&Bl[lrow][lcol]      = *(const short8*)(Brow0 + k0);
        *(short8*)&Bl[lrow + 64][lcol] = *(const short8*)(Brow1 + k0);
        __syncthreads();

        short8 af[4], bfr[4];
        #pragma unroll
        for (int m = 0; m < 4; m++) af[m]  = *(const short8*)&Al[wr * 64 + m * 16 + fr][fk];
        #pragma unroll
        for (int n = 0; n < 4; n++) bfr[n] = *(const short8*)&Bl[wc * 64 + n * 16 + fr][fk];
        #pragma unroll
        for (int m = 0; m < 4; m++)
            #pragma unroll
            for (int n = 0; n < 4; n++)
                acc[m][n] = mfma16(af[m], bfr[n], acc[m][n]);
        __syncthreads();
    }

    const int r0 = (lane >> 4) * 4;
    #pragma unroll
    for (int m = 0; m < 4; m++) {
        #pragma unroll
        for (int i = 0; i < 4; i++) {
            const int grow = bm + wr * 64 + m * 16 + r0 + i;
            #pragma unroll
            for (int n = 0; n < 4; n++) {
                const int gcol = bn + wc * 64 + n * 16 + fr;
                float v = acc[m][n][i] + bias[gcol];
                if (gcol < scale_ncols) v *= 0.125f;
                if (OUT_BF16) Cb[(size_t)grow * N + gcol] = f2bf(v);
                else          Cf[(size_t)grow * N + gcol] = v;
            }
        }
    }
}

// ---------------- causal flash attention v3: swapped QK^T, in-register P ----------
// grid 1024 blocks; block = 4 waves; wave owns 32 q rows. KV tile = 64.
// S^T = mfma(K, Q): lane (fg=lane>>4, fr=lane&15) holds q=fr, kv=fc*16+fg*4+i.
// V stored kv-bit-permuted (slot s: s5=kv5, s4=kv3, s3=kv2, s2=kv4, s1:0=kv1:0)
// + granule XOR swizzle, so P stays in registers (cvt_pk words = PV A-fragment).
__global__ __launch_bounds__(256, 3) void attn_fwd(
    const u16* __restrict__ qkv,   // [M_TOK][3C] bf16 (Q pre-scaled by 0.125)
    u16* __restrict__ out)         // [M_TOK][C] bf16
{
    __shared__ u16 Kl[64][72];     // [kv][d], +8 pad
    __shared__ u16 Vp[64 * 64];    // [d][kv-slot], XOR-swizzled granules

    const int tid  = threadIdx.x;
    const int lane = tid & 63;
    const int wv   = tid >> 6;
    const int bid  = blockIdx.x;
    const int head = bid >> 4;
    const int b = head >> 4, h = head & 15;
    const int qt = 15 - (((bid & 15) + ((bid >> 8) << 2)) & 15);
    const int tok0 = b * T_;
    const int q0 = qt * 128 + wv * 32;
    const int fr = lane & 15;
    const int fg = lane >> 4;
    const int fk = fg * 8;

    // Q fragments (reused as B-operand; layout identical to A-operand)
    short8 aq[2][2];
    #pragma unroll
    for (int rg = 0; rg < 2; rg++) {
        const u16* qp = qkv + (size_t)(tok0 + q0 + rg * 16 + fr) * (3 * C_) + h * HD;
        aq[rg][0] = *(const short8*)(qp + fk);
        aq[rg][1] = *(const short8*)(qp + 32 + fk);
    }

    f32x4 oacc[2][4] = {};
    float mrow[2] = { -INFINITY, -INFINITY };
    float lsum[2] = { 0.f, 0.f };

    // staging indices
    const int kvr = tid >> 2;              // kv row 0..63
    const int kc  = (tid & 3) * 8;         // d chunk base
    const int s_  = (kvr & 32) | (((kvr >> 2) & 3) << 3) | (((kvr >> 4) & 1) << 2) | (kvr & 3);
    const int vgcol = s_ >> 3;             // logical granule 0..7
    const int vso   = s_ & 7;

    short8 kreg0, kreg1, vreg0, vreg1;

#define LOAD_TILE(kt_) { \
    const u16* kp = qkv + (size_t)(tok0 + (kt_) * 64 + kvr) * (3 * C_) + C_ + h * HD + kc; \
    kreg0 = *(const short8*)kp;        kreg1 = *(const short8*)(kp + 32); \
    vreg0 = *(const short8*)(kp + C_); vreg1 = *(const short8*)(kp + C_ + 32); }

#define WRITE_TILE() { \
    *(short8*)&Kl[kvr][kc]      = kreg0; \
    *(short8*)&Kl[kvr][kc + 32] = kreg1; \
    _Pragma("unroll") \
    for (int j = 0; j < 8; j++) { \
        Vp[(kc + j)      * 64 + (((vgcol ^ j) & 7) << 3) + vso] = (u16)vreg0[j]; \
        Vp[(kc + 32 + j) * 64 + (((vgcol ^ j) & 7) << 3) + vso] = (u16)vreg1[j]; } }

    LOAD_TILE(0); WRITE_TILE(); __syncthreads();

    const int ntiles = 2 * qt + 2;
    for (int kt = 0; kt < ntiles; ++kt) {
        const bool havenext = (kt + 1 < ntiles);
        if (havenext) LOAD_TILE(kt + 1);

        if (kt * 64 <= q0 + 31) {
            #pragma unroll
            for (int rg = 0; rg < 2; rg++) {
                f32x4 s[4] = {};
                __builtin_amdgcn_s_setprio(1);
                #pragma unroll
                for (int fc = 0; fc < 4; fc++) {
                    const short8 k0 = *(const short8*)&Kl[fc * 16 + fr][fk];
                    const short8 k1 = *(const short8*)&Kl[fc * 16 + fr][32 + fk];
                    s[fc] = mfma16(k0, aq[rg][0], s[fc]);
                    s[fc] = mfma16(k1, aq[rg][1], s[fc]);
                }
                __builtin_amdgcn_s_setprio(0);

                const int qg = q0 + rg * 16 + fr;
                if (kt * 64 + 63 > q0 + rg * 16) {     // diagonal tile: apply mask
                    #pragma unroll
                    for (int fc = 0; fc < 4; fc++)
                        #pragma unroll
                        for (int i = 0; i < 4; i++)
                            if (kt * 64 + fc * 16 + fg * 4 + i > qg) s[fc][i] = -INFINITY;
                }
                float mx = mrow[rg];
                #pragma unroll
                for (int fc = 0; fc < 4; fc++)
                    #pragma unroll
                    for (int i = 0; i < 4; i++)
                        mx = fmaxf(mx, s[fc][i]);
                mx = fmaxf(mx, __shfl_xor(mx, 16, 64));
                mx = fmaxf(mx, __shfl_xor(mx, 32, 64));
                const float alpha = __expf(mrow[rg] - mx);
                mrow[rg] = mx;

                float ps = 0.f;
                u32x4 wl[2];
                #pragma unroll
                for (int fc = 0; fc < 4; fc++) {
                    const float p0 = __expf(s[fc][0] - mx), p1 = __expf(s[fc][1] - mx);
                    const float p2 = __expf(s[fc][2] - mx), p3 = __expf(s[fc][3] - mx);
                    ps += (p0 + p1) + (p2 + p3);
                    wl[fc >> 1][(fc & 1) * 2 + 0] = cvtpk(p0, p1);
                    wl[fc >> 1][(fc & 1) * 2 + 1] = cvtpk(p2, p3);
                }
                ps += __shfl_xor(ps, 16, 64);
                ps += __shfl_xor(ps, 32, 64);
                lsum[rg] = lsum[rg] * alpha + ps;

                float av[4];
                #pragma unroll
                for (int i = 0; i < 4; i++) av[i] = __shfl(alpha, (fg << 2) + i, 64);
                #pragma unroll
                for (int df = 0; df < 4; df++)
                    #pragma unroll
                    for (int i = 0; i < 4; i++) oacc[rg][df][i] *= av[i];

                __builtin_amdgcn_s_setprio(1);
                #pragma unroll
                for (int c = 0; c < 2; c++) {
                    const short8 ap = __builtin_bit_cast(short8, wl[c]);
                    #pragma unroll
                    for (int df = 0; df < 4; df++) {
                        const short8 bv = *(const short8*)
                            &Vp[(df * 16 + fr) * 64 + ((((c << 2) + fg) ^ (fr & 7)) << 3)];
                        oacc[rg][df] = mfma16(ap, bv, oacc[rg][df]);
                    }
                }
                __builtin_amdgcn_s_setprio(0);
            }
        }
        __syncthreads();
        if (havenext) WRITE_TILE();
        __syncthreads();
    }

    // epilogue: oacc row q = fg*4+i; lsum lives at lane fr=q (any group)
    #pragma unroll
    for (int rg = 0; rg < 2; rg++) {
        #pragma unroll
        for (int i = 0; i < 4; i++) {
            const float li = __shfl(lsum[rg], (fg << 2) + i, 64);
            const float inv = 1.f / li;
            const int tokn = tok0 + q0 + rg * 16 + fg * 4 + i;
            #pragma unroll
            for (int df = 0; df < 4; df++)
                out[(size_t)tokn * C_ + h * HD + df * 16 + fr] = f2bf(oacc[rg][df][i] * inv);
        }
    }
#undef LOAD_TILE
#undef WRITE_TILE
}

extern "C" void kernel_launch(void* const* d_in, const int* in_sizes, int n_in,
                              void* d_out, int out_size, void* d_ws, size_t ws_size,
                              hipStream_t stream) {
    const float* hs    = (const float*)d_in[0];
    const float* w_qkv = (const float*)d_in[1];
    const float* b_qkv = (const float*)d_in[2];
    const float* w_o   = (const float*)d_in[3];
    const float* b_o   = (const float*)d_in[4];
    float* out = (float*)d_out;

    u16* Xb    = (u16*)d_ws;                            // [8192][1024]
    u16* WqkvT = Xb    + (size_t)M_TOK * C_;            // [3072][1024]
    u16* WoT   = WqkvT + (size_t)3 * C_ * C_;           // [1024][1024]
    u16* QKV   = WoT   + (size_t)C_ * C_;               // [8192][3072]
    u16* AO    = QKV   + (size_t)M_TOK * 3 * C_;        // [8192][1024]

    {
        const int n4 = M_TOK * C_ / 4;
        convert_x<<<(n4 + 255) / 256, 256, 0, stream>>>(hs, Xb, n4);
        dim3 tb(32, 8);
        transpose_bf16<<<dim3(3 * C_ / 32, C_ / 32), tb, 0, stream>>>(w_qkv, WqkvT, C_, 3 * C_);
        transpose_bf16<<<dim3(C_ / 32, C_ / 32), tb, 0, stream>>>(w_o, WoT, C_, C_);
    }

    // QKV projection; Q columns (gcol < C_) pre-scaled by 0.125 = HD^-0.5
    gemm_bt<1><<<dim3(3 * C_ / 128, M_TOK / 128), 256, 0, stream>>>(
        Xb, WqkvT, b_qkv, QKV, nullptr, M_TOK, 3 * C_, C_, C_);

    attn_fwd<<<dim3(T_ / 128 * B_ * NH), 256, 0, stream>>>(QKV, AO);

    gemm_bt<0><<<dim3(C_ / 128, M_TOK / 128), 256, 0, stream>>>(
        AO, WoT, b_o, nullptr, out, M_TOK, C_, C_, 0);
}

// Round 7
// 243.763 us; speedup vs baseline: 1.6138x; 1.0216x over previous
//
#include <hip/hip_runtime.h>
#include <hip/hip_bf16.h>

#define B_ 4
#define T_ 2048
#define C_ 1024
#define NH 16
#define HD 64
#define M_TOK (B_*T_)   // 8192

typedef unsigned short u16;
typedef __bf16 bf16x8 __attribute__((ext_vector_type(8)));
typedef short short8 __attribute__((ext_vector_type(8)));
typedef float f32x4 __attribute__((ext_vector_type(4)));
typedef unsigned u32x4 __attribute__((ext_vector_type(4)));
typedef unsigned short u16x4 __attribute__((ext_vector_type(4)));

static __device__ __forceinline__ u16 f2bf(float f) {
    union { float f; unsigned u; } a; a.f = f;
    unsigned u = a.u;
    u = u + 0x7fff + ((u >> 16) & 1);   // RNE
    return (u16)(u >> 16);
}

static __device__ __forceinline__ unsigned cvtpk(float lo, float hi) {
    unsigned r;
    asm("v_cvt_pk_bf16_f32 %0, %1, %2" : "=v"(r) : "v"(lo), "v"(hi));
    return r;
}

static __device__ __forceinline__ f32x4 mfma16(short8 a, short8 b, f32x4 c) {
    return __builtin_amdgcn_mfma_f32_16x16x32_bf16(
        __builtin_bit_cast(bf16x8, a), __builtin_bit_cast(bf16x8, b), c, 0, 0, 0);
}

// async global -> LDS, 16B per lane; lds base must be wave-uniform
#define GLOAD16(gp, lp) __builtin_amdgcn_global_load_lds( \
    (const __attribute__((address_space(1))) unsigned*)(const void*)(gp), \
    (__attribute__((address_space(3))) unsigned*)(void*)(lp), 16, 0, 0)

// ---------------- elementwise fp32 -> bf16 ----------------
__global__ void convert_x(const float* __restrict__ src, u16* __restrict__ dst, int n4) {
    int i = blockIdx.x * blockDim.x + threadIdx.x;
    if (i < n4) {
        const float4 v = *(const float4*)(src + (size_t)i * 4);
        u16x4 o;
        o[0] = f2bf(v.x); o[1] = f2bf(v.y); o[2] = f2bf(v.z); o[3] = f2bf(v.w);
        *(u16x4*)(dst + (size_t)i * 4) = o;
    }
}

// ---------------- transpose fp32 [rows][cols] -> bf16 [cols][rows] ----------------
__global__ void transpose_bf16(const float* __restrict__ src, u16* __restrict__ dst,
                               int rows, int cols) {
    __shared__ float tile[32][33];
    const int c0 = blockIdx.x * 32, r0 = blockIdx.y * 32;
    const int tx = threadIdx.x, ty = threadIdx.y;
    #pragma unroll
    for (int j = ty; j < 32; j += 8)
        tile[j][tx] = src[(size_t)(r0 + j) * cols + c0 + tx];
    __syncthreads();
    #pragma unroll
    for (int j = ty; j < 32; j += 8)
        dst[(size_t)(c0 + j) * rows + r0 + tx] = f2bf(tile[tx][j]);
}

// ---------------- bf16 GEMM (m97 structure): C = A * Bt^T + bias ----------------
// 128x128 tile, BK=32, global_load_lds width-16 staging into linear [128][32] LDS.
template<int OUT_BF16>
__global__ __launch_bounds__(256) void gemm_bt(
    const u16* __restrict__ A,    // [M][K] bf16
    const u16* __restrict__ Bt,   // [N][K] bf16
    const float* __restrict__ bias, // [N]
    u16* __restrict__ Cb, float* __restrict__ Cf,
    int M, int N, int K, int scale_ncols)
{
    __shared__ u16 Al[128 * 32];
    __shared__ u16 Bl[128 * 32];
    const int tid  = threadIdx.x;
    const int lane = tid & 63;
    const int w    = tid >> 6;
    const int wr   = w >> 1, wc = w & 1;
    const int bm   = blockIdx.y * 128, bn = blockIdx.x * 128;

    f32x4 acc[4][4] = {};

    // staging: lane covers row (w*16 + lane/4), cols (lane%4)*8 of each 64-row half
    const int srow = (w << 4) + (lane >> 2);
    const int scol = (lane & 3) * 8;
    const u16* gA0 = A  + (size_t)(bm + srow) * K + scol;
    const u16* gA1 = gA0 + (size_t)64 * K;
    const u16* gB0 = Bt + (size_t)(bn + srow) * K + scol;
    const u16* gB1 = gB0 + (size_t)64 * K;
    u16* lA0 = &Al[(w << 4) * 32];          // wave-uniform bases
    u16* lA1 = &Al[(64 + (w << 4)) * 32];
    u16* lB0 = &Bl[(w << 4) * 32];
    u16* lB1 = &Bl[(64 + (w << 4)) * 32];

    const int fr = lane & 15;
    const int fk = (lane >> 4) * 8;

    for (int k0 = 0; k0 < K; k0 += 32) {
        GLOAD16(gA0 + k0, lA0);
        GLOAD16(gA1 + k0, lA1);
        GLOAD16(gB0 + k0, lB0);
        GLOAD16(gB1 + k0, lB1);
        __syncthreads();   // drains vmcnt -> LDS valid

        short8 af[4], bfr[4];
        #pragma unroll
        for (int m = 0; m < 4; m++) af[m]  = *(const short8*)&Al[(wr * 64 + m * 16 + fr) * 32 + fk];
        #pragma unroll
        for (int n = 0; n < 4; n++) bfr[n] = *(const short8*)&Bl[(wc * 64 + n * 16 + fr) * 32 + fk];
        #pragma unroll
        for (int m = 0; m < 4; m++)
            #pragma unroll
            for (int n = 0; n < 4; n++)
                acc[m][n] = mfma16(af[m], bfr[n], acc[m][n]);
        __syncthreads();
    }

    const int r0 = (lane >> 4) * 4;
    #pragma unroll
    for (int m = 0; m < 4; m++) {
        #pragma unroll
        for (int i = 0; i < 4; i++) {
            const int grow = bm + wr * 64 + m * 16 + r0 + i;
            #pragma unroll
            for (int n = 0; n < 4; n++) {
                const int gcol = bn + wc * 64 + n * 16 + fr;
                float v = acc[m][n][i] + bias[gcol];
                if (gcol < scale_ncols) v *= 0.125f;
                if (OUT_BF16) Cb[(size_t)grow * N + gcol] = f2bf(v);
                else          Cf[(size_t)grow * N + gcol] = v;
            }
        }
    }
}

// ---------------- causal flash attention (round-3 verbatim, proven) -------------
// grid 1024 blocks; block = 4 waves; wave owns 32 q rows. KV tile = 64.
// S^T = mfma(K, Q): lane (fg=lane>>4, fr=lane&15) holds q=fr, kv=fc*16+fg*4+i.
// V stored kv-bit-permuted (slot s: s5=kv5, s4=kv3, s3=kv2, s2=kv4, s1:0=kv1:0)
// + granule XOR swizzle, so P stays in registers (cvt_pk words = PV A-fragment).
__global__ __launch_bounds__(256, 3) void attn_fwd(
    const u16* __restrict__ qkv,   // [M_TOK][3C] bf16 (Q pre-scaled by 0.125)
    u16* __restrict__ out)         // [M_TOK][C] bf16
{
    __shared__ u16 Kl[64][72];     // [kv][d], +8 pad
    __shared__ u16 Vp[64 * 64];    // [d][kv-slot], XOR-swizzled granules

    const int tid  = threadIdx.x;
    const int lane = tid & 63;
    const int wv   = tid >> 6;
    const int bid  = blockIdx.x;
    const int head = bid >> 4;
    const int b = head >> 4, h = head & 15;
    const int qt = 15 - (((bid & 15) + ((bid >> 8) << 2)) & 15);
    const int tok0 = b * T_;
    const int q0 = qt * 128 + wv * 32;
    const int fr = lane & 15;
    const int fg = lane >> 4;
    const int fk = fg * 8;

    // Q fragments (reused as B-operand; layout identical to A-operand)
    short8 aq[2][2];
    #pragma unroll
    for (int rg = 0; rg < 2; rg++) {
        const u16* qp = qkv + (size_t)(tok0 + q0 + rg * 16 + fr) * (3 * C_) + h * HD;
        aq[rg][0] = *(const short8*)(qp + fk);
        aq[rg][1] = *(const short8*)(qp + 32 + fk);
    }

    f32x4 oacc[2][4] = {};
    float mrow[2] = { -INFINITY, -INFINITY };
    float lsum[2] = { 0.f, 0.f };

    // staging indices
    const int kvr = tid >> 2;              // kv row 0..63
    const int kc  = (tid & 3) * 8;         // d chunk base
    const int s_  = (kvr & 32) | (((kvr >> 2) & 3) << 3) | (((kvr >> 4) & 1) << 2) | (kvr & 3);
    const int vgcol = s_ >> 3;             // logical granule 0..7
    const int vso   = s_ & 7;

    short8 kreg0, kreg1, vreg0, vreg1;

#define LOAD_TILE(kt_) { \
    const u16* kp = qkv + (size_t)(tok0 + (kt_) * 64 + kvr) * (3 * C_) + C_ + h * HD + kc; \
    kreg0 = *(const short8*)kp;        kreg1 = *(const short8*)(kp + 32); \
    vreg0 = *(const short8*)(kp + C_); vreg1 = *(const short8*)(kp + C_ + 32); }

#define WRITE_TILE() { \
    *(short8*)&Kl[kvr][kc]      = kreg0; \
    *(short8*)&Kl[kvr][kc + 32] = kreg1; \
    _Pragma("unroll") \
    for (int j = 0; j < 8; j++) { \
        Vp[(kc + j)      * 64 + (((vgcol ^ j) & 7) << 3) + vso] = (u16)vreg0[j]; \
        Vp[(kc + 32 + j) * 64 + (((vgcol ^ j) & 7) << 3) + vso] = (u16)vreg1[j]; } }

    LOAD_TILE(0); WRITE_TILE(); __syncthreads();

    const int ntiles = 2 * qt + 2;
    for (int kt = 0; kt < ntiles; ++kt) {
        const bool havenext = (kt + 1 < ntiles);
        if (havenext) LOAD_TILE(kt + 1);

        if (kt * 64 <= q0 + 31) {
            #pragma unroll
            for (int rg = 0; rg < 2; rg++) {
                f32x4 s[4] = {};
                __builtin_amdgcn_s_setprio(1);
                #pragma unroll
                for (int fc = 0; fc < 4; fc++) {
                    const short8 k0 = *(const short8*)&Kl[fc * 16 + fr][fk];
                    const short8 k1 = *(const short8*)&Kl[fc * 16 + fr][32 + fk];
                    s[fc] = mfma16(k0, aq[rg][0], s[fc]);
                    s[fc] = mfma16(k1, aq[rg][1], s[fc]);
                }
                __builtin_amdgcn_s_setprio(0);

                const int qg = q0 + rg * 16 + fr;
                if (kt * 64 + 63 > q0 + rg * 16) {     // diagonal tile: apply mask
                    #pragma unroll
                    for (int fc = 0; fc < 4; fc++)
                        #pragma unroll
                        for (int i = 0; i < 4; i++)
                            if (kt * 64 + fc * 16 + fg * 4 + i > qg) s[fc][i] = -INFINITY;
                }
                float mx = mrow[rg];
                #pragma unroll
                for (int fc = 0; fc < 4; fc++)
                    #pragma unroll
                    for (int i = 0; i < 4; i++)
                        mx = fmaxf(mx, s[fc][i]);
                mx = fmaxf(mx, __shfl_xor(mx, 16, 64));
                mx = fmaxf(mx, __shfl_xor(mx, 32, 64));
                const float alpha = __expf(mrow[rg] - mx);
                mrow[rg] = mx;

                float ps = 0.f;
                u32x4 wl[2];
                #pragma unroll
                for (int fc = 0; fc < 4; fc++) {
                    const float p0 = __expf(s[fc][0] - mx), p1 = __expf(s[fc][1] - mx);
                    const float p2 = __expf(s[fc][2] - mx), p3 = __expf(s[fc][3] - mx);
                    ps += (p0 + p1) + (p2 + p3);
                    wl[fc >> 1][(fc & 1) * 2 + 0] = cvtpk(p0, p1);
                    wl[fc >> 1][(fc & 1) * 2 + 1] = cvtpk(p2, p3);
                }
                ps += __shfl_xor(ps, 16, 64);
                ps += __shfl_xor(ps, 32, 64);
                lsum[rg] = lsum[rg] * alpha + ps;

                float av[4];
                #pragma unroll
                for (int i = 0; i < 4; i++) av[i] = __shfl(alpha, (fg << 2) + i, 64);
                #pragma unroll
                for (int df = 0; df < 4; df++)
                    #pragma unroll
                    for (int i = 0; i < 4; i++) oacc[rg][df][i] *= av[i];

                __builtin_amdgcn_s_setprio(1);
                #pragma unroll
                for (int c = 0; c < 2; c++) {
                    const short8 ap = __builtin_bit_cast(short8, wl[c]);
                    #pragma unroll
                    for (int df = 0; df < 4; df++) {
                        const short8 bv = *(const short8*)
                            &Vp[(df * 16 + fr) * 64 + ((((c << 2) + fg) ^ (fr & 7)) << 3)];
                        oacc[rg][df] = mfma16(ap, bv, oacc[rg][df]);
                    }
                }
                __builtin_amdgcn_s_setprio(0);
            }
        }
        __syncthreads();
        if (havenext) WRITE_TILE();
        __syncthreads();
    }

    // epilogue: oacc row q = fg*4+i; lsum lives at lane fr=q (any group)
    #pragma unroll
    for (int rg = 0; rg < 2; rg++) {
        #pragma unroll
        for (int i = 0; i < 4; i++) {
            const float li = __shfl(lsum[rg], (fg << 2) + i, 64);
            const float inv = 1.f / li;
            const int tokn = tok0 + q0 + rg * 16 + fg * 4 + i;
            #pragma unroll
            for (int df = 0; df < 4; df++)
                out[(size_t)tokn * C_ + h * HD + df * 16 + fr] = f2bf(oacc[rg][df][i] * inv);
        }
    }
#undef LOAD_TILE
#undef WRITE_TILE
}

extern "C" void kernel_launch(void* const* d_in, const int* in_sizes, int n_in,
                              void* d_out, int out_size, void* d_ws, size_t ws_size,
                              hipStream_t stream) {
    const float* hs    = (const float*)d_in[0];
    const float* w_qkv = (const float*)d_in[1];
    const float* b_qkv = (const float*)d_in[2];
    const float* w_o   = (const float*)d_in[3];
    const float* b_o   = (const float*)d_in[4];
    float* out = (float*)d_out;

    u16* Xb    = (u16*)d_ws;                            // [8192][1024]
    u16* WqkvT = Xb    + (size_t)M_TOK * C_;            // [3072][1024]
    u16* WoT   = WqkvT + (size_t)3 * C_ * C_;           // [1024][1024]
    u16* QKV   = WoT   + (size_t)C_ * C_;               // [8192][3072]
    u16* AO    = QKV   + (size_t)M_TOK * 3 * C_;        // [8192][1024]

    {
        const int n4 = M_TOK * C_ / 4;
        convert_x<<<(n4 + 255) / 256, 256, 0, stream>>>(hs, Xb, n4);
        dim3 tb(32, 8);
        transpose_bf16<<<dim3(3 * C_ / 32, C_ / 32), tb, 0, stream>>>(w_qkv, WqkvT, C_, 3 * C_);
        transpose_bf16<<<dim3(C_ / 32, C_ / 32), tb, 0, stream>>>(w_o, WoT, C_, C_);
    }

    // QKV projection; Q columns (gcol < C_) pre-scaled by 0.125 = HD^-0.5
    gemm_bt<1><<<dim3(3 * C_ / 128, M_TOK / 128), 256, 0, stream>>>(
        Xb, WqkvT, b_qkv, QKV, nullptr, M_TOK, 3 * C_, C_, C_);

    attn_fwd<<<dim3(T_ / 128 * B_ * NH), 256, 0, stream>>>(QKV, AO);

    gemm_bt<0><<<dim3(C_ / 128, M_TOK / 128), 256, 0, stream>>>(
        AO, WoT, b_o, nullptr, out, M_TOK, C_, C_, 0);
}